// Round 4
// baseline (465.771 us; speedup 1.0000x reference)
//
#include <hip/hip_runtime.h>

// LSTMForecaster: B=4096, T=512, D=1, H=64, 2 layers + FC(64->1).
// R20 = R19 barrier lockstep, WAVE ROLES MERGED: 8 waves, each owns 8 L0-units
//   AND 8 L1-units (was 8 L0-waves + 8 L1-waves).
//   Evidence: R19 win validated the model (MfmaUtil 22.8 ~ predicted 24.8 for
//   96 MFMA/step). Remaining 1880 cyc/step decomposition: LDS read pipe ~576
//   cyc (48 b128 burst post-barrier), wave imbalance under lockstep (L1 waves
//   2x L0 work -> L0 idles), and L1's h0-read duplicating L0's.
//   Merge: with the 1-step skew, the L1-part at iter tt consumes h0(tt-1) --
//   exactly the fragment the same wave's L0-part loads. So each wave: read h0
//   + h1 (4 b128, was 6 across two waves), 4 L0-MFMA + 8 L1-MFMA reusing h0
//   frags in registers, two independent cell2 chains (ILP: L1 MFMAs overlap
//   L0 cell; trans chains interleave). LDS reads 48->32/step, balanced waves,
//   barrier width 16->8. Same MFMA/trans totals; numerically identical.
//   Iteration tt: L0-part computes h0(tt) from h0(tt-1); L1-part computes
//   h1(tt-1) from h0(tt-1) and h1(tt-2). 513 iters, one barrier each.
//   If regress: revert to R19 (420us); if neutral -> instruction diet next.

#define TT 512
#define HH 64
#define NB 16
#define XP 516

typedef __bf16 bf16_t;
typedef bf16_t bf16x8 __attribute__((ext_vector_type(8)));
typedef float  f32x4  __attribute__((ext_vector_type(4)));
typedef float  f32x2  __attribute__((ext_vector_type(2)));

#define MFMA(A, B, C) __builtin_amdgcn_mfma_f32_16x16x32_bf16((A), (B), (C), 0, 0, 0)
#define RCPF(x) __builtin_amdgcn_rcpf(x)

#if __has_builtin(__builtin_amdgcn_exp2f)
#define EXP2F(x) __builtin_amdgcn_exp2f(x)
#else
__device__ __forceinline__ float EXP2F(float x) {
    float r;
    asm volatile("v_exp_f32 %0, %1" : "=v"(r) : "v"(x));
    return r;
}
#endif

#define SC_IFO (-1.4426950408889634f)   // -log2(e)
#define SC_G   ( 2.8853900817779268f)   // +2*log2(e)

__device__ __forceinline__ unsigned short f32_to_bf16_rne(float f) {
    unsigned int u = __builtin_bit_cast(unsigned int, f);
    unsigned int r = u + 0x7fffu + ((u >> 16) & 1u);
    return (unsigned short)(r >> 16);
}
__device__ __forceinline__ bf16_t bits_to_bf16(unsigned short u) {
    return __builtin_bit_cast(bf16_t, u);
}
// single-term weight frag with per-row scale folded in (RNE)
__device__ __forceinline__ void build_frag_scaled(const float* __restrict__ p, float sc,
                                                  bf16x8& w) {
    const float4 a = *(const float4*)p;
    const float4 b = *(const float4*)(p + 4);
    float v[8] = {a.x, a.y, a.z, a.w, b.x, b.y, b.z, b.w};
#pragma unroll
    for (int jj = 0; jj < 8; ++jj)
        w[jj] = bits_to_bf16(f32_to_bf16_rne(v[jj] * sc));
}

__device__ __forceinline__ f32x2 exp2v(f32x2 v) {
    f32x2 r; r[0] = EXP2F(v[0]); r[1] = EXP2F(v[1]); return r;
}
__device__ __forceinline__ f32x2 rcpv(f32x2 v) {
    f32x2 r; r[0] = RCPF(v[0]); r[1] = RCPF(v[1]); return r;
}
// Two cells on PRE-SCALED gates (is,fs,os scaled -log2e; gs scaled +2log2e).
__device__ __forceinline__ f32x2 cell2(const f32x4 a0, const f32x4 a1, f32x2* c) {
    f32x2 is = {a0[0], a1[0]}, fs = {a0[1], a1[1]};
    f32x2 gs = {a0[2], a1[2]}, os = {a0[3], a1[3]};
    const f32x2 pf = exp2v(fs);
    const f32x2 fg = rcpv(1.0f + pf);
    const f32x2 pi = exp2v(is);
    const f32x2 e2 = exp2v(gs);
    const f32x2 z  = (e2 - 1.0f) * rcpv((1.0f + pi) * (1.0f + e2));
    *c = fg * (*c) + z;
    const f32x2 po  = exp2v(os);
    const f32x2 e2c = exp2v((*c) * SC_G);
    return (e2c - 1.0f) * rcpv((1.0f + po) * (1.0f + e2c));
}

// per-iteration lockstep: drain LDS writes, hw barrier, fence the compiler
#define STEP_BARRIER()                                                          \
    do {                                                                        \
        asm volatile("s_waitcnt lgkmcnt(0)" ::: "memory");                      \
        __builtin_amdgcn_s_barrier();                                           \
        asm volatile("" ::: "memory");                                          \
    } while (0)

__global__ __launch_bounds__(512, 2)
void lstm_1t_kernel(const float* __restrict__ x,
                    const float* __restrict__ Wih0, const float* __restrict__ Whh0,
                    const float* __restrict__ bih0, const float* __restrict__ bhh0,
                    const float* __restrict__ Wih1, const float* __restrict__ Whh1,
                    const float* __restrict__ bih1, const float* __restrict__ bhh1,
                    const float* __restrict__ Wfc,  const float* __restrict__ bfc,
                    float* __restrict__ out)
{
    __shared__ float xbuf[NB][XP];                   // 33 KB
    __shared__ unsigned short h0r[8][NB][64];        // 16 KB ring, slot t&7
    __shared__ unsigned short h1r[2][NB][64];        // 4 KB ring, slot t&1
    __shared__ float h1fin[HH][NB + 1];              // 4.25 KB

    const int tid  = threadIdx.x;
    const int wv   = tid >> 6;       // 0..7: each wave owns L0 units [8w,8w+8)
    const int lane = tid & 63;       //       AND L1 units [8w,8w+8)
    const int m    = lane & 15;      // batch col (B/C frag) & A-frag row-in-tile
    const int q    = lane >> 4;      // C-frag unit_local; A/B k-quad
    const int m7   = m & 7;
    const int b0   = blockIdx.x * NB;

    // ---- stage x (coalesced float4) ----
    for (int i = tid; i < NB * TT / 4; i += 512) {
        const int b  = i >> 7;
        const int t4 = i & 127;
        *(float4*)&xbuf[b][t4 * 4] = *(const float4*)&x[(size_t)(b0 + b) * TT + t4 * 4];
    }
    // ---- zero rings (h(-1)/h(-2) served by zeroed slots) ----
    for (int i = tid; i < 8 * NB * 64; i += 512) (&h0r[0][0][0])[i] = 0;
    for (int i = tid; i < 2 * NB * 64; i += 512) (&h1r[0][0][0])[i] = 0;

    // ---- per-lane read offsets (shorts within one slot = 1024) ----
    int roff[2];
#pragma unroll
    for (int kt = 0; kt < 2; ++kt)
        roff[kt] = m * 64 + (((4 * kt + q) ^ m7) * 8);

    const int gate_m = m & 3;
    const float scA  = (gate_m == 2) ? SC_G : SC_IFO;
    unsigned short* const H0 = &h0r[0][0][0];
    unsigned short* const H1 = &h1r[0][0][0];

    // ===== per-wave constants: L0 part (units [8w,8w+8)) =====
    const int w = wv;
    bf16x8 Ah0[2][2];                   // [tau][kt] of Whh0
    f32x4 bb0s[2], wx0s[2];
    int woff0[2];
#pragma unroll
    for (int tau = 0; tau < 2; ++tau) {
        const int rowA = 64 * gate_m + 8 * w + 4 * tau + (m >> 2);
#pragma unroll
        for (int kt = 0; kt < 2; ++kt)
            build_frag_scaled(&Whh0[rowA * HH + kt * 32 + q * 8], scA, Ah0[tau][kt]);
#pragma unroll
        for (int r = 0; r < 4; ++r) {
            const int row = 64 * r + 8 * w + 4 * tau + q;
            const float sc = (r == 2) ? SC_G : SC_IFO;
            bb0s[tau][r] = (bih0[row] + bhh0[row]) * sc;
            wx0s[tau][r] = Wih0[row] * sc;
        }
        const int u = 8 * w + 4 * tau + q;
        woff0[tau] = m * 64 + (((u >> 3) ^ m7) * 8) + (u & 7);
    }

    // ===== per-wave constants: L1 part (units [8w,8w+8)) =====
    bf16x8 Ah1[2][4];    // [tau][kt]: kt0-1 Wih1 (eats h0), kt2-3 Whh1 (eats h1)
    f32x4 bb1s[2];
    int woff1[2], uu[2];
#pragma unroll
    for (int tau = 0; tau < 2; ++tau) {
        const int rowA = 64 * gate_m + 8 * w + 4 * tau + (m >> 2);
#pragma unroll
        for (int kt = 0; kt < 2; ++kt)
            build_frag_scaled(&Wih1[rowA * HH + kt * 32 + q * 8], scA, Ah1[tau][kt]);
#pragma unroll
        for (int kt = 0; kt < 2; ++kt)
            build_frag_scaled(&Whh1[rowA * HH + kt * 32 + q * 8], scA, Ah1[tau][2 + kt]);
#pragma unroll
        for (int r = 0; r < 4; ++r) {
            const int row = 64 * r + 8 * w + 4 * tau + q;
            const float sc = (r == 2) ? SC_G : SC_IFO;
            bb1s[tau][r] = (bih1[row] + bhh1[row]) * sc;
        }
        const int u = 8 * w + 4 * tau + q;
        uu[tau]   = u;
        woff1[tau] = m * 64 + (((u >> 3) ^ m7) * 8) + (u & 7);
    }

    f32x2 cA  = {0.f, 0.f};   // L0 cell state
    f32x2 c1v = {0.f, 0.f};   // L1 cell state

    __syncthreads();     // staging visible (drains vmcnt too)

#pragma unroll 1
    for (int tt = 0; tt <= TT; ++tt) {
        // ---- reads: h0(tt-1) serves BOTH Whh0 (L0) and Wih1 (L1, tm=tt-1);
        //      h1(tt-2) serves Whh1. Boundary iters read zeroed slots (unused).
        const int rs0 = ((tt - 1) & 7) * (NB * 64);
        const int rs1 = ((tt - 2) & 1) * (NB * 64);
        bf16x8 h0[2], h1[2];
        h0[0] = *(const bf16x8*)(H0 + rs0 + roff[0]);
        h0[1] = *(const bf16x8*)(H0 + rs0 + roff[1]);
        h1[0] = *(const bf16x8*)(H1 + rs1 + roff[0]);
        h1[1] = *(const bf16x8*)(H1 + rs1 + roff[1]);

        if (tt < TT) {
            // ===== L0 part: h0(tt) from h0(tt-1) =====
            const float xv = xbuf[m][tt];
            f32x4 a0[2];
#pragma unroll
            for (int tau = 0; tau < 2; ++tau) {
#pragma unroll
                for (int r = 0; r < 4; ++r)
                    a0[tau][r] = __builtin_fmaf(xv, wx0s[tau][r], bb0s[tau][r]);
                a0[tau] = MFMA(Ah0[tau][0], h0[0], a0[tau]);
                a0[tau] = MFMA(Ah0[tau][1], h0[1], a0[tau]);
            }
            const f32x2 hv0 = cell2(a0[0], a0[1], &cA);
            const int ws = (tt & 7) * (NB * 64);
            H0[ws + woff0[0]] = f32_to_bf16_rne(hv0[0]);
            H0[ws + woff0[1]] = f32_to_bf16_rne(hv0[1]);
        }

        if (tt >= 1) {
            // ===== L1 part: h1(tm) from h0(tm), h1(tm-1); tm = tt-1 =====
            const int tm = tt - 1;
            f32x4 a1[2];
#pragma unroll
            for (int tau = 0; tau < 2; ++tau) {
                a1[tau] = MFMA(Ah1[tau][0], h0[0], bb1s[tau]);   // Wih1 . h0(tm)
                a1[tau] = MFMA(Ah1[tau][1], h0[1], a1[tau]);
                a1[tau] = MFMA(Ah1[tau][2], h1[0], a1[tau]);     // + Whh1 . h1(tm-1)
                a1[tau] = MFMA(Ah1[tau][3], h1[1], a1[tau]);
            }
            const f32x2 hv1 = cell2(a1[0], a1[1], &c1v);
            if (tm == TT - 1) {                 // exact fp32 h1(T-1) for FC
                h1fin[uu[0]][m] = hv1[0];
                h1fin[uu[1]][m] = hv1[1];
            }
            const int ws = (tm & 1) * (NB * 64);
            H1[ws + woff1[0]] = f32_to_bf16_rne(hv1[0]);
            H1[ws + woff1[1]] = f32_to_bf16_rne(hv1[1]);
        }

        STEP_BARRIER();
    }

    __syncthreads();

    // ---- FC epilogue: out[b] = h1(T-1)[b] . Wfc + bfc ----
    if (tid < NB) {
        float sacc = bfc[0];
#pragma unroll
        for (int u = 0; u < HH; ++u) sacc = fmaf(h1fin[u][tid], Wfc[u], sacc);
        out[b0 + tid] = sacc;
    }
}

extern "C" void kernel_launch(void* const* d_in, const int* in_sizes, int n_in,
                              void* d_out, int out_size, void* d_ws, size_t ws_size,
                              hipStream_t stream) {
    const float* x    = (const float*)d_in[0];
    const float* Wih0 = (const float*)d_in[1];
    const float* Whh0 = (const float*)d_in[2];
    const float* bih0 = (const float*)d_in[3];
    const float* bhh0 = (const float*)d_in[4];
    const float* Wih1 = (const float*)d_in[5];
    const float* Whh1 = (const float*)d_in[6];
    const float* bih1 = (const float*)d_in[7];
    const float* bhh1 = (const float*)d_in[8];
    const float* Wfc  = (const float*)d_in[9];
    const float* bfc  = (const float*)d_in[10];

    lstm_1t_kernel<<<dim3(4096 / NB), dim3(512), 0, stream>>>(
        x, Wih0, Whh0, bih0, bhh0, Wih1, Whh1, bih1, bhh1, Wfc, bfc, (float*)d_out);
}